// Round 8
// baseline (157.734 us; speedup 1.0000x reference)
//
#include <hip/hip_runtime.h>
#include <math.h>

#define FT_IN  40960
#define FFT_IN 640
#define FT_OUT 256
#define NA     30
#define NSLICE 8          // one 32-col slice per XCD (blockIdx % 8 -> XCD round-robin)
#define BPB    64         // boards per gather block (256 thr = 64 boards x 4 lanes)
#define PD     6          // ft pipeline depth (iterations in flight; 2 loads each)

typedef _Float16 h2 __attribute__((ext_vector_type(2)));
typedef unsigned u32x4 __attribute__((ext_vector_type(4)));

__device__ __forceinline__ h2 u2h2(unsigned u) {
    union { unsigned u; h2 h; } c; c.u = u; return c.h;
}
__device__ __forceinline__ unsigned pkh(float a, float b) {
    union { h2 h; unsigned u; } c; c.h = h2{(_Float16)a, (_Float16)b}; return c.u;
}

// ---------- fused prep: f32->f16 sliced convert (ft, fft) + index pack ----------
// sliced layout: [NSLICE][nrows][32 f16]; one row-slice = 64 B
__device__ __forceinline__ void conv_block(const float* __restrict__ src,
                                           unsigned* __restrict__ dst,
                                           int nrows, int bid, int tid)
{
    int t = bid * 256 + tid;
    int total = nrows * 32;               // 32 uint4 chunks per row
    if (t >= total) return;
    int r = t >> 5, g = t & 31;           // chunk g: cols [8g, 8g+8)
    int s = g >> 2, d = g & 3;            // slice, uint4-within-slice
    const float4* sp = (const float4*)(src + (size_t)r * FT_OUT + g * 8);
    float4 v0 = sp[0], v1 = sp[1];
    uint4 u;
    u.x = pkh(v0.x, v0.y); u.y = pkh(v0.z, v0.w);
    u.z = pkh(v1.x, v1.y); u.w = pkh(v1.z, v1.w);
    ((uint4*)dst)[((size_t)s * nrows + r) * 4 + d] = u;
}

__global__ __launch_bounds__(256) void prep(
    const float* __restrict__ ft_w, const float* __restrict__ fft_w,
    const int* __restrict__ stm, const int* __restrict__ nstm,
    const int* __restrict__ fstm, const int* __restrict__ fnstm,
    unsigned* __restrict__ ft_o, unsigned* __restrict__ fft_o,
    ushort4* __restrict__ pidx, int n_boards, int nb_ft, int nb_fft)
{
    int bid = blockIdx.x;
    if (bid < nb_ft) {
        conv_block(ft_w, ft_o, FT_IN, bid, threadIdx.x);
    } else if (bid < nb_ft + nb_fft) {
        conv_block(fft_w, fft_o, FFT_IN, bid - nb_ft, threadIdx.x);
    } else {
        int t = (bid - nb_ft - nb_fft) * 256 + (int)threadIdx.x;
        int total = n_boards * NA;
        if (t < total) {
            int board = t / NA, a = t - board * NA;
            ushort4 v;
            v.x = (unsigned short)stm[t];  v.y = (unsigned short)nstm[t];
            v.z = (unsigned short)fstm[t]; v.w = (unsigned short)fnstm[t];
            pidx[(size_t)a * n_boards + board] = v;   // transposed [a][board]
        }
    }
}

// ---------- gather: asm-pipelined ft loads (explicit vmcnt), idx+fft in LDS ----------
// 256 threads = 64 boards x 4 lanes; lane owns 8 cols (16 B) of the 32-col slice
__global__ __launch_bounds__(256) void nnue_gather(
    const uint2* __restrict__ pidx,      // [NA][n_boards] packed ushort4
    const char* __restrict__ ft, const char* __restrict__ fft,
    const float* __restrict__ ft_b, const float* __restrict__ fft_b,
    const float* __restrict__ out_w, float* __restrict__ partial, int n_boards)
{
    __shared__ uint2 lidx[NA][BPB];       // 15 KB
    __shared__ u32x4 lfft[FFT_IN * 4];    // 40 KB; chunk c of row r at slot c ^ ((r>>1)&3)
    const int slice = blockIdx.x & (NSLICE - 1);
    const int group = blockIdx.x >> 3;
    const int tid = (int)threadIdx.x;

    {   // stage indices (coalesced per-a rows of 64 uint2)
        for (int i = tid; i < NA * BPB; i += 256) {
            int a = i >> 6, b = i & 63;
            int bd = group * BPB + b;
            uint2 v;
            if (bd < n_boards) v = pidx[(size_t)a * n_boards + bd];
            else { v.x = 0; v.y = 0; }
            lidx[a][b] = v;
        }
        // stage fft slice with bank-spreading XOR swizzle
        const u32x4* fsrc = (const u32x4*)(fft + (size_t)slice * FFT_IN * 64);
        for (int i = tid; i < FFT_IN * 4; i += 256) {
            int r = i >> 2, c = i & 3;
            lfft[(r << 2) + (c ^ ((r >> 1) & 3))] = fsrc[i];
        }
    }
    __syncthreads();

    const int sub = tid >> 2, ql = tid & 3;
    int board = group * BPB + sub;
    const bool active = board < n_boards;
    const unsigned qlo = (unsigned)(ql << 4);
    const unsigned long long ftbase =
        (unsigned long long)(ft + (size_t)slice * FT_IN * 64);
    const int col = slice * 32 + ql * 8;

    h2 z = h2{(_Float16)0.f, (_Float16)0.f};
    h2 a0[4] = {z, z, z, z};     // stm half
    h2 a1[4] = {z, z, z, z};     // nstm half

    u32x4 fs[PD], fn[PD];
    // prologue: issue ft loads for iterations 0..PD-1 (12 in flight)
    #pragma unroll
    for (int a = 0; a < PD; ++a) {
        uint2 iv = lidx[a][sub];
        unsigned o0 = ((iv.x & 0xFFFFu) << 6) + qlo;
        unsigned o1 = ((iv.x >> 16) << 6) + qlo;
        asm volatile("global_load_dwordx4 %0, %1, %2"
                     : "=v"(fs[a]) : "v"(o0), "s"(ftbase));
        asm volatile("global_load_dwordx4 %0, %1, %2"
                     : "=v"(fn[a]) : "v"(o1), "s"(ftbase));
    }

#define STEP(A)                                                              \
    {                                                                        \
        uint2 ivA = lidx[(A)][sub];                                          \
        unsigned rz = ivA.y & 0xFFFFu, rw = ivA.y >> 16;                     \
        u32x4 g0 = lfft[(rz << 2) + (ql ^ ((rz >> 1) & 3))];                 \
        u32x4 g1 = lfft[(rw << 2) + (ql ^ ((rw >> 1) & 3))];                 \
        asm volatile("s_waitcnt vmcnt(%2)"                                   \
                     : "+v"(fs[(A) % PD]), "+v"(fn[(A) % PD])                \
                     : "n"(2 * ((NA - (A)) < PD ? (NA - (A)) : PD) - 2));    \
        u32x4 u0 = fs[(A) % PD], u1 = fn[(A) % PD];                          \
        a0[0] += u2h2(u0.x); a0[1] += u2h2(u0.y);                            \
        a0[2] += u2h2(u0.z); a0[3] += u2h2(u0.w);                            \
        a1[0] += u2h2(u1.x); a1[1] += u2h2(u1.y);                            \
        a1[2] += u2h2(u1.z); a1[3] += u2h2(u1.w);                            \
        a0[0] += u2h2(g0.x); a0[1] += u2h2(g0.y);                            \
        a0[2] += u2h2(g0.z); a0[3] += u2h2(g0.w);                            \
        a1[0] += u2h2(g1.x); a1[1] += u2h2(g1.y);                            \
        a1[2] += u2h2(g1.z); a1[3] += u2h2(g1.w);                            \
        if ((A) + PD < NA) {                                                 \
            uint2 ivB = lidx[(A) + PD][sub];                                 \
            unsigned o0 = ((ivB.x & 0xFFFFu) << 6) + qlo;                    \
            unsigned o1 = ((ivB.x >> 16) << 6) + qlo;                        \
            asm volatile("global_load_dwordx4 %0, %1, %2"                    \
                         : "=v"(fs[(A) % PD]) : "v"(o0), "s"(ftbase));       \
            asm volatile("global_load_dwordx4 %0, %1, %2"                    \
                         : "=v"(fn[(A) % PD]) : "v"(o1), "s"(ftbase));       \
        }                                                                    \
    }

    STEP(0)  STEP(1)  STEP(2)  STEP(3)  STEP(4)  STEP(5)
    STEP(6)  STEP(7)  STEP(8)  STEP(9)  STEP(10) STEP(11)
    STEP(12) STEP(13) STEP(14) STEP(15) STEP(16) STEP(17)
    STEP(18) STEP(19) STEP(20) STEP(21) STEP(22) STEP(23)
    STEP(24) STEP(25) STEP(26) STEP(27) STEP(28) STEP(29)
#undef STEP

    // epilogue: f32 bias + clip + partial dot
    float h0[8], h1[8];
    #pragma unroll
    for (int i = 0; i < 4; ++i) {
        h0[2*i] = (float)a0[i].x; h0[2*i+1] = (float)a0[i].y;
        h1[2*i] = (float)a1[i].x; h1[2*i+1] = (float)a1[i].y;
    }
    const float4* bfp = (const float4*)(ft_b  + col);
    const float4* bgp = (const float4*)(fft_b + col);
    float4 bf0 = bfp[0], bf1 = bfp[1], bg0 = bgp[0], bg1 = bgp[1];
    float bias[8] = {bf0.x+bg0.x, bf0.y+bg0.y, bf0.z+bg0.z, bf0.w+bg0.w,
                     bf1.x+bg1.x, bf1.y+bg1.y, bf1.z+bg1.z, bf1.w+bg1.w};
    const float4* w0p = (const float4*)(out_w + col);
    const float4* w1p = (const float4*)(out_w + FT_OUT + col);
    float4 w00 = w0p[0], w01 = w0p[1], w10 = w1p[0], w11 = w1p[1];
    float w0[8] = {w00.x, w00.y, w00.z, w00.w, w01.x, w01.y, w01.z, w01.w};
    float w1[8] = {w10.x, w10.y, w10.z, w10.w, w11.x, w11.y, w11.z, w11.w};

    float p = 0.f;
    #pragma unroll
    for (int i = 0; i < 8; ++i) {
        p += fminf(fmaxf(h0[i] + bias[i], 0.f), 1.f) * w0[i];
        p += fminf(fmaxf(h1[i] + bias[i], 0.f), 1.f) * w1[i];
    }
    p += __shfl_xor(p, 1, 64);
    p += __shfl_xor(p, 2, 64);
    if (active && ql == 0) partial[(size_t)slice * n_boards + board] = p;
}

// ---------- final: sum 8 partials + sigmoid ----------
__global__ __launch_bounds__(256) void nnue_final(
    const float* __restrict__ partial, const float* __restrict__ out_b,
    float* __restrict__ out, int n)
{
    int b = blockIdx.x * blockDim.x + threadIdx.x;
    if (b >= n) return;
    float zv = out_b[0];
    #pragma unroll
    for (int s = 0; s < NSLICE; ++s) zv += partial[(size_t)s * n + b];
    out[b] = 1.0f / (1.0f + expf(-zv));
}

// ---------- fallback: direct f32 gather (if ws too small) ----------
__global__ __launch_bounds__(256) void nnue_fwd_direct(
    const int* __restrict__ stm_idx, const int* __restrict__ nstm_idx,
    const int* __restrict__ f_stm_idx, const int* __restrict__ f_nstm_idx,
    const float* __restrict__ ft_w, const float* __restrict__ ft_b,
    const float* __restrict__ fft_w, const float* __restrict__ fft_b,
    const float* __restrict__ out_w, const float* __restrict__ out_b,
    float* __restrict__ out, int n_boards)
{
    const int board = (int)((blockIdx.x * blockDim.x + threadIdx.x) >> 6);
    const int lane  = (int)(threadIdx.x & 63);
    if (board >= n_boards) return;
    const int col = lane << 2;
    const float4 ftb  = *(const float4*)(ft_b  + col);
    const float4 fftb = *(const float4*)(fft_b + col);
    float a0x = ftb.x + fftb.x, a0y = ftb.y + fftb.y,
          a0z = ftb.z + fftb.z, a0w = ftb.w + fftb.w;
    float a1x = a0x, a1y = a0y, a1z = a0z, a1w = a0w;
    const int* si  = stm_idx    + (size_t)board * NA;
    const int* ni  = nstm_idx   + (size_t)board * NA;
    const int* fsi = f_stm_idx  + (size_t)board * NA;
    const int* fni = f_nstm_idx + (size_t)board * NA;
    #pragma unroll 5
    for (int a = 0; a < NA; ++a) {
        const float4 r0 = *(const float4*)(ft_w  + (size_t)si[a]  * FT_OUT + col);
        const float4 r1 = *(const float4*)(ft_w  + (size_t)ni[a]  * FT_OUT + col);
        const float4 r2 = *(const float4*)(fft_w + (size_t)fsi[a] * FT_OUT + col);
        const float4 r3 = *(const float4*)(fft_w + (size_t)fni[a] * FT_OUT + col);
        a0x += r0.x + r2.x; a0y += r0.y + r2.y; a0z += r0.z + r2.z; a0w += r0.w + r2.w;
        a1x += r1.x + r3.x; a1y += r1.y + r3.y; a1z += r1.z + r3.z; a1w += r1.w + r3.w;
    }
    a0x = fminf(fmaxf(a0x, 0.f), 1.f); a0y = fminf(fmaxf(a0y, 0.f), 1.f);
    a0z = fminf(fmaxf(a0z, 0.f), 1.f); a0w = fminf(fmaxf(a0w, 0.f), 1.f);
    a1x = fminf(fmaxf(a1x, 0.f), 1.f); a1y = fminf(fmaxf(a1y, 0.f), 1.f);
    a1z = fminf(fmaxf(a1z, 0.f), 1.f); a1w = fminf(fmaxf(a1w, 0.f), 1.f);
    const float4 w0 = *(const float4*)(out_w + col);
    const float4 w1 = *(const float4*)(out_w + FT_OUT + col);
    float p = a0x * w0.x + a0y * w0.y + a0z * w0.z + a0w * w0.w
            + a1x * w1.x + a1y * w1.y + a1z * w1.z + a1w * w1.w;
    #pragma unroll
    for (int off = 32; off > 0; off >>= 1) p += __shfl_down(p, off, 64);
    if (lane == 0) out[board] = 1.0f / (1.0f + expf(-(p + out_b[0])));
}

extern "C" void kernel_launch(void* const* d_in, const int* in_sizes, int n_in,
                              void* d_out, int out_size, void* d_ws, size_t ws_size,
                              hipStream_t stream) {
    const int*   stm_idx    = (const int*)d_in[0];
    const int*   nstm_idx   = (const int*)d_in[1];
    const int*   f_stm_idx  = (const int*)d_in[2];
    const int*   f_nstm_idx = (const int*)d_in[3];
    const float* ft_w  = (const float*)d_in[4];
    const float* ft_b  = (const float*)d_in[5];
    const float* fft_w = (const float*)d_in[6];
    const float* fft_b = (const float*)d_in[7];
    const float* out_w = (const float*)d_in[8];
    const float* out_b = (const float*)d_in[9];
    float* out = (float*)d_out;

    const int n_boards = in_sizes[0] / NA;

    const size_t ft_bytes   = (size_t)FT_IN  * FT_OUT * 2;               // 20.97 MB f16
    const size_t fft_bytes  = (size_t)FFT_IN * FT_OUT * 2;               // 320 KB
    const size_t pidx_bytes = (size_t)n_boards * NA * sizeof(ushort4);   // 3.93 MB
    const size_t part_bytes = (size_t)n_boards * NSLICE * sizeof(float); // 512 KB
    const size_t need = ft_bytes + fft_bytes + pidx_bytes + part_bytes;

    if (ws_size < need) {
        const int grid = (n_boards + 3) / 4;
        nnue_fwd_direct<<<grid, 256, 0, stream>>>(stm_idx, nstm_idx, f_stm_idx, f_nstm_idx,
                                                  ft_w, ft_b, fft_w, fft_b, out_w, out_b,
                                                  out, n_boards);
        return;
    }

    char* wsp = (char*)d_ws;
    unsigned* ws_ft   = (unsigned*)wsp;            wsp += ft_bytes;
    unsigned* ws_fft  = (unsigned*)wsp;            wsp += fft_bytes;
    ushort4*  ws_pidx = (ushort4*)wsp;             wsp += pidx_bytes;
    float*    ws_part = (float*)wsp;

    {   // fused prep: converts + index pack in one dispatch
        const int nb_ft   = FT_IN  * 32 / 256;               // 5120
        const int nb_fft  = FFT_IN * 32 / 256;               // 80
        const int nb_pack = (n_boards * NA + 255) / 256;
        prep<<<nb_ft + nb_fft + nb_pack, 256, 0, stream>>>(
            ft_w, fft_w, stm_idx, nstm_idx, f_stm_idx, f_nstm_idx,
            ws_ft, ws_fft, ws_pidx, n_boards, nb_ft, nb_fft);
    }
    {   // sliced gather
        int groups = (n_boards + BPB - 1) / BPB;
        nnue_gather<<<groups * NSLICE, 256, 0, stream>>>(
            (const uint2*)ws_pidx, (const char*)ws_ft, (const char*)ws_fft,
            ft_b, fft_b, out_w, ws_part, n_boards);
    }
    {   // reduce partials + sigmoid
        nnue_final<<<(n_boards + 255) / 256, 256, 0, stream>>>(ws_part, out_b, out, n_boards);
    }
}

// Round 9
// 151.573 us; speedup vs baseline: 1.0407x; 1.0407x over previous
//
#include <hip/hip_runtime.h>
#include <math.h>

#define FT_IN  40960
#define FFT_IN 640
#define FT_OUT 256
#define NA     30
#define NH     15         // features per half-lane-group
#define NSLICE 8          // one 32-col slice per XCD (blockIdx % 8 -> XCD round-robin)
#define BPB    64         // boards per gather block (512 thr = 64 boards x 8 lanes)
#define PD     6          // ft pipeline depth (iterations in flight; 2 loads each)

typedef _Float16 h2 __attribute__((ext_vector_type(2)));
typedef unsigned u32x4 __attribute__((ext_vector_type(4)));

__device__ __forceinline__ h2 u2h2(unsigned u) {
    union { unsigned u; h2 h; } c; c.u = u; return c.h;
}
__device__ __forceinline__ unsigned pkh(float a, float b) {
    union { h2 h; unsigned u; } c; c.h = h2{(_Float16)a, (_Float16)b}; return c.u;
}
__device__ __forceinline__ h2 foldx4(h2 v) {
    union { h2 h; int i; } c; c.h = v;
    c.i = __shfl_xor(c.i, 4, 64);
    return v + c.h;
}

// ---------- fused prep: f32->f16 sliced convert (ft, fft) + index pack ----------
// sliced layout: [NSLICE][nrows][32 f16]; one row-slice = 64 B
__device__ __forceinline__ void conv_block(const float* __restrict__ src,
                                           unsigned* __restrict__ dst,
                                           int nrows, int bid, int tid)
{
    int t = bid * 256 + tid;
    int total = nrows * 32;               // 32 uint4 chunks per row
    if (t >= total) return;
    int r = t >> 5, g = t & 31;           // chunk g: cols [8g, 8g+8)
    int s = g >> 2, d = g & 3;            // slice, uint4-within-slice
    const float4* sp = (const float4*)(src + (size_t)r * FT_OUT + g * 8);
    float4 v0 = sp[0], v1 = sp[1];
    uint4 u;
    u.x = pkh(v0.x, v0.y); u.y = pkh(v0.z, v0.w);
    u.z = pkh(v1.x, v1.y); u.w = pkh(v1.z, v1.w);
    ((uint4*)dst)[((size_t)s * nrows + r) * 4 + d] = u;
}

__global__ __launch_bounds__(256) void prep(
    const float* __restrict__ ft_w, const float* __restrict__ fft_w,
    const int* __restrict__ stm, const int* __restrict__ nstm,
    const int* __restrict__ fstm, const int* __restrict__ fnstm,
    unsigned* __restrict__ ft_o, unsigned* __restrict__ fft_o,
    ushort4* __restrict__ pidx, int n_boards, int nb_ft, int nb_fft)
{
    int bid = blockIdx.x;
    if (bid < nb_ft) {
        conv_block(ft_w, ft_o, FT_IN, bid, threadIdx.x);
    } else if (bid < nb_ft + nb_fft) {
        conv_block(fft_w, fft_o, FFT_IN, bid - nb_ft, threadIdx.x);
    } else {
        int t = (bid - nb_ft - nb_fft) * 256 + (int)threadIdx.x;
        int total = n_boards * NA;
        if (t < total) {
            int board = t / NA, a = t - board * NA;
            ushort4 v;
            v.x = (unsigned short)stm[t];  v.y = (unsigned short)nstm[t];
            v.z = (unsigned short)fstm[t]; v.w = (unsigned short)fnstm[t];
            pidx[(size_t)a * n_boards + board] = v;   // transposed [a][board]
        }
    }
}

// ---------- gather: 8 lanes/board feature-split, asm vmcnt pipeline, padded lfft ----------
// 512 threads = 64 boards x 8 lanes; lane = (half, ql): half picks features
// [0,15) or [15,30), ql picks 8 cols (16 B) of the 32-col slice.
__global__ __launch_bounds__(512, 4) void nnue_gather(
    const uint2* __restrict__ pidx,      // [NA][n_boards] packed ushort4
    const char* __restrict__ ft, const char* __restrict__ fft,
    const float* __restrict__ ft_b, const float* __restrict__ fft_b,
    const float* __restrict__ out_w, float* __restrict__ partial, int n_boards)
{
    __shared__ uint2 lidx[NA * BPB];                    // 15360 B
    __shared__ u32x4 lfft[FFT_IN * 4 + FFT_IN / 2];     // 46080 B; row r at 4r+(r>>1)
    const int slice = blockIdx.x & (NSLICE - 1);
    const int group = blockIdx.x >> 3;
    const int tid = (int)threadIdx.x;

    for (int i = tid; i < NA * BPB; i += 512) {         // [a][board] rows of 64 uint2
        int b = i & 63;
        int bd = group * BPB + b;
        uint2 v; v.x = 0u; v.y = 0u;
        if (bd < n_boards) v = pidx[(size_t)(i >> 6) * n_boards + bd];
        lidx[i] = v;
    }
    {   // stage fft slice with padded row stride (start bank cycles all 8 quads)
        const u32x4* fsrc = (const u32x4*)(fft + (size_t)slice * FFT_IN * 64);
        for (int i = tid; i < FFT_IN * 4; i += 512) {
            int r = i >> 2, c = i & 3;
            lfft[(r << 2) + (r >> 1) + c] = fsrc[i];
        }
    }
    __syncthreads();

    const int sub  = tid >> 3;           // board within block
    const int ql   = tid & 3;
    const int hoff = ((tid >> 2) & 1) * NH;
    int board = group * BPB + sub;
    const bool active = board < n_boards;
    const unsigned qlo = (unsigned)(ql << 4);
    const unsigned long long ftbase =
        (unsigned long long)(ft + (size_t)slice * FT_IN * 64);
    const int col = slice * 32 + ql * 8;

    h2 z = h2{(_Float16)0.f, (_Float16)0.f};
    h2 a0[4] = {z, z, z, z};     // stm half
    h2 a1[4] = {z, z, z, z};     // nstm half

    u32x4 fs[PD], fn[PD];
    #pragma unroll
    for (int a = 0; a < PD; ++a) {
        uint2 iv = lidx[(hoff + a) * BPB + sub];
        unsigned o0 = ((iv.x & 0xFFFFu) << 6) + qlo;
        unsigned o1 = ((iv.x >> 16) << 6) + qlo;
        asm volatile("global_load_dwordx4 %0, %1, %2"
                     : "=v"(fs[a]) : "v"(o0), "s"(ftbase));
        asm volatile("global_load_dwordx4 %0, %1, %2"
                     : "=v"(fn[a]) : "v"(o1), "s"(ftbase));
    }

#define STEP(A)                                                              \
    {                                                                        \
        uint2 ivA = lidx[(hoff + (A)) * BPB + sub];                          \
        unsigned rz = ivA.y & 0xFFFFu, rw = ivA.y >> 16;                     \
        u32x4 g0 = lfft[(rz << 2) + (rz >> 1) + ql];                         \
        u32x4 g1 = lfft[(rw << 2) + (rw >> 1) + ql];                         \
        asm volatile("s_waitcnt vmcnt(%2)"                                   \
                     : "+v"(fs[(A) % PD]), "+v"(fn[(A) % PD])                \
                     : "n"(2 * ((NH - (A)) < PD ? (NH - (A)) : PD) - 2));    \
        u32x4 u0 = fs[(A) % PD], u1 = fn[(A) % PD];                          \
        a0[0] += u2h2(u0.x); a0[1] += u2h2(u0.y);                            \
        a0[2] += u2h2(u0.z); a0[3] += u2h2(u0.w);                            \
        a1[0] += u2h2(u1.x); a1[1] += u2h2(u1.y);                            \
        a1[2] += u2h2(u1.z); a1[3] += u2h2(u1.w);                            \
        a0[0] += u2h2(g0.x); a0[1] += u2h2(g0.y);                            \
        a0[2] += u2h2(g0.z); a0[3] += u2h2(g0.w);                            \
        a1[0] += u2h2(g1.x); a1[1] += u2h2(g1.y);                            \
        a1[2] += u2h2(g1.z); a1[3] += u2h2(g1.w);                            \
        if ((A) + PD < NH) {                                                 \
            uint2 ivB = lidx[(hoff + (A) + PD) * BPB + sub];                 \
            unsigned o0 = ((ivB.x & 0xFFFFu) << 6) + qlo;                    \
            unsigned o1 = ((ivB.x >> 16) << 6) + qlo;                        \
            asm volatile("global_load_dwordx4 %0, %1, %2"                    \
                         : "=v"(fs[(A) % PD]) : "v"(o0), "s"(ftbase));       \
            asm volatile("global_load_dwordx4 %0, %1, %2"                    \
                         : "=v"(fn[(A) % PD]) : "v"(o1), "s"(ftbase));       \
        }                                                                    \
    }

    STEP(0)  STEP(1)  STEP(2)  STEP(3)  STEP(4)
    STEP(5)  STEP(6)  STEP(7)  STEP(8)  STEP(9)
    STEP(10) STEP(11) STEP(12) STEP(13) STEP(14)
#undef STEP

    // fold the two feature-halves (raw sums, BEFORE bias+clip)
    #pragma unroll
    for (int j = 0; j < 4; ++j) { a0[j] = foldx4(a0[j]); a1[j] = foldx4(a1[j]); }

    // epilogue: f32 bias + clip + partial dot
    float h0[8], h1[8];
    #pragma unroll
    for (int i = 0; i < 4; ++i) {
        h0[2*i] = (float)a0[i].x; h0[2*i+1] = (float)a0[i].y;
        h1[2*i] = (float)a1[i].x; h1[2*i+1] = (float)a1[i].y;
    }
    const float4* bfp = (const float4*)(ft_b  + col);
    const float4* bgp = (const float4*)(fft_b + col);
    float4 bf0 = bfp[0], bf1 = bfp[1], bg0 = bgp[0], bg1 = bgp[1];
    float bias[8] = {bf0.x+bg0.x, bf0.y+bg0.y, bf0.z+bg0.z, bf0.w+bg0.w,
                     bf1.x+bg1.x, bf1.y+bg1.y, bf1.z+bg1.z, bf1.w+bg1.w};
    const float4* w0p = (const float4*)(out_w + col);
    const float4* w1p = (const float4*)(out_w + FT_OUT + col);
    float4 w00 = w0p[0], w01 = w0p[1], w10 = w1p[0], w11 = w1p[1];
    float w0[8] = {w00.x, w00.y, w00.z, w00.w, w01.x, w01.y, w01.z, w01.w};
    float w1[8] = {w10.x, w10.y, w10.z, w10.w, w11.x, w11.y, w11.z, w11.w};

    float p = 0.f;
    #pragma unroll
    for (int i = 0; i < 8; ++i) {
        p += fminf(fmaxf(h0[i] + bias[i], 0.f), 1.f) * w0[i];
        p += fminf(fmaxf(h1[i] + bias[i], 0.f), 1.f) * w1[i];
    }
    p += __shfl_xor(p, 1, 64);
    p += __shfl_xor(p, 2, 64);
    if (active && (tid & 7) == 0)
        partial[(size_t)slice * n_boards + board] = p;
}

// ---------- final: sum 8 partials + sigmoid ----------
__global__ __launch_bounds__(256) void nnue_final(
    const float* __restrict__ partial, const float* __restrict__ out_b,
    float* __restrict__ out, int n)
{
    int b = blockIdx.x * blockDim.x + threadIdx.x;
    if (b >= n) return;
    float zv = out_b[0];
    #pragma unroll
    for (int s = 0; s < NSLICE; ++s) zv += partial[(size_t)s * n + b];
    out[b] = 1.0f / (1.0f + expf(-zv));
}

// ---------- fallback: direct f32 gather (if ws too small) ----------
__global__ __launch_bounds__(256) void nnue_fwd_direct(
    const int* __restrict__ stm_idx, const int* __restrict__ nstm_idx,
    const int* __restrict__ f_stm_idx, const int* __restrict__ f_nstm_idx,
    const float* __restrict__ ft_w, const float* __restrict__ ft_b,
    const float* __restrict__ fft_w, const float* __restrict__ fft_b,
    const float* __restrict__ out_w, const float* __restrict__ out_b,
    float* __restrict__ out, int n_boards)
{
    const int board = (int)((blockIdx.x * blockDim.x + threadIdx.x) >> 6);
    const int lane  = (int)(threadIdx.x & 63);
    if (board >= n_boards) return;
    const int col = lane << 2;
    const float4 ftb  = *(const float4*)(ft_b  + col);
    const float4 fftb = *(const float4*)(fft_b + col);
    float a0x = ftb.x + fftb.x, a0y = ftb.y + fftb.y,
          a0z = ftb.z + fftb.z, a0w = ftb.w + fftb.w;
    float a1x = a0x, a1y = a0y, a1z = a0z, a1w = a0w;
    const int* si  = stm_idx    + (size_t)board * NA;
    const int* ni  = nstm_idx   + (size_t)board * NA;
    const int* fsi = f_stm_idx  + (size_t)board * NA;
    const int* fni = f_nstm_idx + (size_t)board * NA;
    #pragma unroll 5
    for (int a = 0; a < NA; ++a) {
        const float4 r0 = *(const float4*)(ft_w  + (size_t)si[a]  * FT_OUT + col);
        const float4 r1 = *(const float4*)(ft_w  + (size_t)ni[a]  * FT_OUT + col);
        const float4 r2 = *(const float4*)(fft_w + (size_t)fsi[a] * FT_OUT + col);
        const float4 r3 = *(const float4*)(fft_w + (size_t)fni[a] * FT_OUT + col);
        a0x += r0.x + r2.x; a0y += r0.y + r2.y; a0z += r0.z + r2.z; a0w += r0.w + r2.w;
        a1x += r1.x + r3.x; a1y += r1.y + r3.y; a1z += r1.z + r3.z; a1w += r1.w + r3.w;
    }
    a0x = fminf(fmaxf(a0x, 0.f), 1.f); a0y = fminf(fmaxf(a0y, 0.f), 1.f);
    a0z = fminf(fmaxf(a0z, 0.f), 1.f); a0w = fminf(fmaxf(a0w, 0.f), 1.f);
    a1x = fminf(fmaxf(a1x, 0.f), 1.f); a1y = fminf(fmaxf(a1y, 0.f), 1.f);
    a1z = fminf(fmaxf(a1z, 0.f), 1.f); a1w = fminf(fmaxf(a1w, 0.f), 1.f);
    const float4 w0 = *(const float4*)(out_w + col);
    const float4 w1 = *(const float4*)(out_w + FT_OUT + col);
    float p = a0x * w0.x + a0y * w0.y + a0z * w0.z + a0w * w0.w
            + a1x * w1.x + a1y * w1.y + a1z * w1.z + a1w * w1.w;
    #pragma unroll
    for (int off = 32; off > 0; off >>= 1) p += __shfl_down(p, off, 64);
    if (lane == 0) out[board] = 1.0f / (1.0f + expf(-(p + out_b[0])));
}

extern "C" void kernel_launch(void* const* d_in, const int* in_sizes, int n_in,
                              void* d_out, int out_size, void* d_ws, size_t ws_size,
                              hipStream_t stream) {
    const int*   stm_idx    = (const int*)d_in[0];
    const int*   nstm_idx   = (const int*)d_in[1];
    const int*   f_stm_idx  = (const int*)d_in[2];
    const int*   f_nstm_idx = (const int*)d_in[3];
    const float* ft_w  = (const float*)d_in[4];
    const float* ft_b  = (const float*)d_in[5];
    const float* fft_w = (const float*)d_in[6];
    const float* fft_b = (const float*)d_in[7];
    const float* out_w = (const float*)d_in[8];
    const float* out_b = (const float*)d_in[9];
    float* out = (float*)d_out;

    const int n_boards = in_sizes[0] / NA;

    const size_t ft_bytes   = (size_t)FT_IN  * FT_OUT * 2;               // 20.97 MB f16
    const size_t fft_bytes  = (size_t)FFT_IN * FT_OUT * 2;               // 320 KB
    const size_t pidx_bytes = (size_t)n_boards * NA * sizeof(ushort4);   // 3.93 MB
    const size_t part_bytes = (size_t)n_boards * NSLICE * sizeof(float); // 512 KB
    const size_t need = ft_bytes + fft_bytes + pidx_bytes + part_bytes;

    if (ws_size < need) {
        const int grid = (n_boards + 3) / 4;
        nnue_fwd_direct<<<grid, 256, 0, stream>>>(stm_idx, nstm_idx, f_stm_idx, f_nstm_idx,
                                                  ft_w, ft_b, fft_w, fft_b, out_w, out_b,
                                                  out, n_boards);
        return;
    }

    char* wsp = (char*)d_ws;
    unsigned* ws_ft   = (unsigned*)wsp;            wsp += ft_bytes;
    unsigned* ws_fft  = (unsigned*)wsp;            wsp += fft_bytes;
    ushort4*  ws_pidx = (ushort4*)wsp;             wsp += pidx_bytes;
    float*    ws_part = (float*)wsp;

    {   // fused prep: converts + index pack in one dispatch
        const int nb_ft   = FT_IN  * 32 / 256;               // 5120
        const int nb_fft  = FFT_IN * 32 / 256;               // 80
        const int nb_pack = (n_boards * NA + 255) / 256;
        prep<<<nb_ft + nb_fft + nb_pack, 256, 0, stream>>>(
            ft_w, fft_w, stm_idx, nstm_idx, f_stm_idx, f_nstm_idx,
            ws_ft, ws_fft, ws_pidx, n_boards, nb_ft, nb_fft);
    }
    {   // sliced gather
        int groups = (n_boards + BPB - 1) / BPB;
        nnue_gather<<<groups * NSLICE, 512, 0, stream>>>(
            (const uint2*)ws_pidx, (const char*)ws_ft, (const char*)ws_fft,
            ft_b, fft_b, out_w, ws_part, n_boards);
    }
    {   // reduce partials + sigmoid
        nnue_final<<<(n_boards + 255) / 256, 256, 0, stream>>>(ws_part, out_b, out, n_boards);
    }
}

// Round 10
// 139.368 us; speedup vs baseline: 1.1318x; 1.0876x over previous
//
#include <hip/hip_runtime.h>
#include <math.h>

#define FT_IN  40960
#define FFT_IN 640
#define FT_OUT 256
#define NA     30
#define NSLICE 4          // 64-col slices; XCD x serves slice x%4 (blockIdx%8 round-robin)
#define BPB    128        // boards per gather block (1024 thr = 128 boards x 8 lanes)

typedef _Float16 h2 __attribute__((ext_vector_type(2)));
typedef unsigned u32x4 __attribute__((ext_vector_type(4)));

__device__ __forceinline__ h2 u2h2(unsigned u) {
    union { unsigned u; h2 h; } c; c.u = u; return c.h;
}
__device__ __forceinline__ unsigned pkh(float a, float b) {
    union { h2 h; unsigned u; } c; c.h = h2{(_Float16)a, (_Float16)b}; return c.u;
}

// ---------- fused prep: f32->f16 sliced convert (ft, fft) + index pack ----------
// sliced layout: [NSLICE][nrows][64 f16]; one row-slice = 128 B
__device__ __forceinline__ void conv_block(const float* __restrict__ src,
                                           unsigned* __restrict__ dst,
                                           int nrows, int bid, int tid)
{
    int t = bid * 256 + tid;
    int total = nrows * 32;               // 32 uint4 chunks (8 cols each) per row
    if (t >= total) return;
    int r = t >> 5, g = t & 31;           // chunk g: cols [8g, 8g+8)
    int s = g >> 3, d = g & 7;            // slice (64 cols = 8 chunks), chunk-within-slice
    const float4* sp = (const float4*)(src + (size_t)r * FT_OUT + g * 8);
    float4 v0 = sp[0], v1 = sp[1];
    uint4 u;
    u.x = pkh(v0.x, v0.y); u.y = pkh(v0.z, v0.w);
    u.z = pkh(v1.x, v1.y); u.w = pkh(v1.z, v1.w);
    ((uint4*)dst)[((size_t)s * nrows + r) * 8 + d] = u;
}

__global__ __launch_bounds__(256) void prep(
    const float* __restrict__ ft_w, const float* __restrict__ fft_w,
    const int* __restrict__ stm, const int* __restrict__ nstm,
    const int* __restrict__ fstm, const int* __restrict__ fnstm,
    unsigned* __restrict__ ft_o, unsigned* __restrict__ fft_o,
    ushort4* __restrict__ pidx, int n_boards, int nb_ft, int nb_fft)
{
    int bid = blockIdx.x;
    if (bid < nb_ft) {
        conv_block(ft_w, ft_o, FT_IN, bid, threadIdx.x);
    } else if (bid < nb_ft + nb_fft) {
        conv_block(fft_w, fft_o, FFT_IN, bid - nb_ft, threadIdx.x);
    } else {
        int t = (bid - nb_ft - nb_fft) * 256 + (int)threadIdx.x;
        int total = n_boards * NA;
        if (t < total) {
            int board = t / NA, a = t - board * NA;
            ushort4 v;
            v.x = (unsigned short)stm[t];  v.y = (unsigned short)nstm[t];
            v.z = (unsigned short)fstm[t]; v.w = (unsigned short)fnstm[t];
            pidx[(size_t)a * n_boards + board] = v;   // transposed [a][board]
        }
    }
}

// ---------- gather: 128 B row requests (one L2 line each), fft+idx in dynamic LDS ----------
// 1024 threads = 128 boards x 8 lanes; lane owns 8 cols (16 B) of the 64-col slice
__global__ __launch_bounds__(1024, 4) void nnue_gather(
    const uint2* __restrict__ pidx,      // [NA][n_boards] packed ushort4
    const char* __restrict__ ft, const char* __restrict__ fft,
    const float* __restrict__ ft_b, const float* __restrict__ fft_b,
    const float* __restrict__ out_w, float* __restrict__ partial, int n_boards)
{
    extern __shared__ char smem[];
    uint2* lidx = (uint2*)smem;                        // [NA][BPB] = 30720 B
    u32x4* lfft = (u32x4*)(smem + NA * BPB * 8);       // [FFT_IN][8] = 81920 B (uniform banks)
    const int slice = blockIdx.x & (NSLICE - 1);
    const int group = blockIdx.x >> 2;
    const int tid = (int)threadIdx.x;

    for (int i = tid; i < NA * BPB; i += 1024) {       // [a][board] rows of 128 uint2
        int b = i & (BPB - 1);
        int bd = group * BPB + b;
        uint2 v; v.x = 0u; v.y = 0u;
        if (bd < n_boards) v = pidx[(size_t)(i >> 7) * n_boards + bd];
        lidx[i] = v;
    }
    {   // stage fft slice (linear; rows are 8 consecutive uint4 = all 32 banks)
        const u32x4* fsrc = (const u32x4*)(fft + (size_t)slice * FFT_IN * 128);
        for (int i = tid; i < FFT_IN * 8; i += 1024)
            lfft[i] = fsrc[i];
    }
    __syncthreads();

    const int sub = tid >> 3, ql = tid & 7;
    int board = group * BPB + sub;
    const bool active = board < n_boards;
    const unsigned qlo = (unsigned)(ql << 4);
    const char* ftS = ft + (size_t)slice * FT_IN * 128 + qlo;
    const int col = slice * 64 + ql * 8;

    h2 z = h2{(_Float16)0.f, (_Float16)0.f};
    h2 a0[4] = {z, z, z, z};     // stm half
    h2 a1[4] = {z, z, z, z};     // nstm half

    #pragma unroll
    for (int a = 0; a < NA; ++a) {
        uint2 iv = lidx[a * BPB + sub];
        u32x4 u0 = *(const u32x4*)(ftS + ((iv.x & 0xFFFFu) << 7));
        u32x4 u1 = *(const u32x4*)(ftS + ((iv.x >> 16) << 7));
        u32x4 g0 = lfft[((iv.y & 0xFFFFu) << 3) + ql];
        u32x4 g1 = lfft[((iv.y >> 16) << 3) + ql];
        a0[0] += u2h2(u0.x); a0[1] += u2h2(u0.y); a0[2] += u2h2(u0.z); a0[3] += u2h2(u0.w);
        a1[0] += u2h2(u1.x); a1[1] += u2h2(u1.y); a1[2] += u2h2(u1.z); a1[3] += u2h2(u1.w);
        a0[0] += u2h2(g0.x); a0[1] += u2h2(g0.y); a0[2] += u2h2(g0.z); a0[3] += u2h2(g0.w);
        a1[0] += u2h2(g1.x); a1[1] += u2h2(g1.y); a1[2] += u2h2(g1.z); a1[3] += u2h2(g1.w);
    }

    // epilogue: f32 bias + clip + partial dot
    float h0[8], h1[8];
    #pragma unroll
    for (int i = 0; i < 4; ++i) {
        h0[2*i] = (float)a0[i].x; h0[2*i+1] = (float)a0[i].y;
        h1[2*i] = (float)a1[i].x; h1[2*i+1] = (float)a1[i].y;
    }
    const float4* bfp = (const float4*)(ft_b  + col);
    const float4* bgp = (const float4*)(fft_b + col);
    float4 bf0 = bfp[0], bf1 = bfp[1], bg0 = bgp[0], bg1 = bgp[1];
    float bias[8] = {bf0.x+bg0.x, bf0.y+bg0.y, bf0.z+bg0.z, bf0.w+bg0.w,
                     bf1.x+bg1.x, bf1.y+bg1.y, bf1.z+bg1.z, bf1.w+bg1.w};
    const float4* w0p = (const float4*)(out_w + col);
    const float4* w1p = (const float4*)(out_w + FT_OUT + col);
    float4 w00 = w0p[0], w01 = w0p[1], w10 = w1p[0], w11 = w1p[1];
    float w0[8] = {w00.x, w00.y, w00.z, w00.w, w01.x, w01.y, w01.z, w01.w};
    float w1[8] = {w10.x, w10.y, w10.z, w10.w, w11.x, w11.y, w11.z, w11.w};

    float p = 0.f;
    #pragma unroll
    for (int i = 0; i < 8; ++i) {
        p += fminf(fmaxf(h0[i] + bias[i], 0.f), 1.f) * w0[i];
        p += fminf(fmaxf(h1[i] + bias[i], 0.f), 1.f) * w1[i];
    }
    p += __shfl_xor(p, 1, 64);
    p += __shfl_xor(p, 2, 64);
    p += __shfl_xor(p, 4, 64);
    if (active && ql == 0)
        partial[(size_t)slice * n_boards + board] = p;
}

// ---------- final: sum 4 partials + sigmoid ----------
__global__ __launch_bounds__(256) void nnue_final(
    const float* __restrict__ partial, const float* __restrict__ out_b,
    float* __restrict__ out, int n)
{
    int b = blockIdx.x * blockDim.x + threadIdx.x;
    if (b >= n) return;
    float zv = out_b[0];
    #pragma unroll
    for (int s = 0; s < NSLICE; ++s) zv += partial[(size_t)s * n + b];
    out[b] = 1.0f / (1.0f + expf(-zv));
}

// ---------- fallback: direct f32 gather (if ws too small) ----------
__global__ __launch_bounds__(256) void nnue_fwd_direct(
    const int* __restrict__ stm_idx, const int* __restrict__ nstm_idx,
    const int* __restrict__ f_stm_idx, const int* __restrict__ f_nstm_idx,
    const float* __restrict__ ft_w, const float* __restrict__ ft_b,
    const float* __restrict__ fft_w, const float* __restrict__ fft_b,
    const float* __restrict__ out_w, const float* __restrict__ out_b,
    float* __restrict__ out, int n_boards)
{
    const int board = (int)((blockIdx.x * blockDim.x + threadIdx.x) >> 6);
    const int lane  = (int)(threadIdx.x & 63);
    if (board >= n_boards) return;
    const int col = lane << 2;
    const float4 ftb  = *(const float4*)(ft_b  + col);
    const float4 fftb = *(const float4*)(fft_b + col);
    float a0x = ftb.x + fftb.x, a0y = ftb.y + fftb.y,
          a0z = ftb.z + fftb.z, a0w = ftb.w + fftb.w;
    float a1x = a0x, a1y = a0y, a1z = a0z, a1w = a0w;
    const int* si  = stm_idx    + (size_t)board * NA;
    const int* ni  = nstm_idx   + (size_t)board * NA;
    const int* fsi = f_stm_idx  + (size_t)board * NA;
    const int* fni = f_nstm_idx + (size_t)board * NA;
    #pragma unroll 5
    for (int a = 0; a < NA; ++a) {
        const float4 r0 = *(const float4*)(ft_w  + (size_t)si[a]  * FT_OUT + col);
        const float4 r1 = *(const float4*)(ft_w  + (size_t)ni[a]  * FT_OUT + col);
        const float4 r2 = *(const float4*)(fft_w + (size_t)fsi[a] * FT_OUT + col);
        const float4 r3 = *(const float4*)(fft_w + (size_t)fni[a] * FT_OUT + col);
        a0x += r0.x + r2.x; a0y += r0.y + r2.y; a0z += r0.z + r2.z; a0w += r0.w + r2.w;
        a1x += r1.x + r3.x; a1y += r1.y + r3.y; a1z += r1.z + r3.z; a1w += r1.w + r3.w;
    }
    a0x = fminf(fmaxf(a0x, 0.f), 1.f); a0y = fminf(fmaxf(a0y, 0.f), 1.f);
    a0z = fminf(fmaxf(a0z, 0.f), 1.f); a0w = fminf(fmaxf(a0w, 0.f), 1.f);
    a1x = fminf(fmaxf(a1x, 0.f), 1.f); a1y = fminf(fmaxf(a1y, 0.f), 1.f);
    a1z = fminf(fmaxf(a1z, 0.f), 1.f); a1w = fminf(fmaxf(a1w, 0.f), 1.f);
    const float4 w0 = *(const float4*)(out_w + col);
    const float4 w1 = *(const float4*)(out_w + FT_OUT + col);
    float p = a0x * w0.x + a0y * w0.y + a0z * w0.z + a0w * w0.w
            + a1x * w1.x + a1y * w1.y + a1z * w1.z + a1w * w1.w;
    #pragma unroll
    for (int off = 32; off > 0; off >>= 1) p += __shfl_down(p, off, 64);
    if (lane == 0) out[board] = 1.0f / (1.0f + expf(-(p + out_b[0])));
}

extern "C" void kernel_launch(void* const* d_in, const int* in_sizes, int n_in,
                              void* d_out, int out_size, void* d_ws, size_t ws_size,
                              hipStream_t stream) {
    const int*   stm_idx    = (const int*)d_in[0];
    const int*   nstm_idx   = (const int*)d_in[1];
    const int*   f_stm_idx  = (const int*)d_in[2];
    const int*   f_nstm_idx = (const int*)d_in[3];
    const float* ft_w  = (const float*)d_in[4];
    const float* ft_b  = (const float*)d_in[5];
    const float* fft_w = (const float*)d_in[6];
    const float* fft_b = (const float*)d_in[7];
    const float* out_w = (const float*)d_in[8];
    const float* out_b = (const float*)d_in[9];
    float* out = (float*)d_out;

    const int n_boards = in_sizes[0] / NA;

    const size_t ft_bytes   = (size_t)FT_IN  * FT_OUT * 2;               // 20.97 MB f16
    const size_t fft_bytes  = (size_t)FFT_IN * FT_OUT * 2;               // 320 KB
    const size_t pidx_bytes = (size_t)n_boards * NA * sizeof(ushort4);   // 3.93 MB
    const size_t part_bytes = (size_t)n_boards * NSLICE * sizeof(float); // 256 KB
    const size_t need = ft_bytes + fft_bytes + pidx_bytes + part_bytes;

    const size_t lds_bytes = (size_t)NA * BPB * 8 + (size_t)FFT_IN * 128; // 112640

    bool ok = (ws_size >= need);
    if (ok) {
        ok = (hipFuncSetAttribute((const void*)nnue_gather,
                                  hipFuncAttributeMaxDynamicSharedMemorySize,
                                  (int)lds_bytes) == hipSuccess);
    }
    if (!ok) {
        const int grid = (n_boards + 3) / 4;
        nnue_fwd_direct<<<grid, 256, 0, stream>>>(stm_idx, nstm_idx, f_stm_idx, f_nstm_idx,
                                                  ft_w, ft_b, fft_w, fft_b, out_w, out_b,
                                                  out, n_boards);
        return;
    }

    char* wsp = (char*)d_ws;
    unsigned* ws_ft   = (unsigned*)wsp;            wsp += ft_bytes;
    unsigned* ws_fft  = (unsigned*)wsp;            wsp += fft_bytes;
    ushort4*  ws_pidx = (ushort4*)wsp;             wsp += pidx_bytes;
    float*    ws_part = (float*)wsp;

    {   // fused prep: converts + index pack in one dispatch
        const int nb_ft   = FT_IN  * 32 / 256;               // 5120
        const int nb_fft  = FFT_IN * 32 / 256;               // 80
        const int nb_pack = (n_boards * NA + 255) / 256;
        prep<<<nb_ft + nb_fft + nb_pack, 256, 0, stream>>>(
            ft_w, fft_w, stm_idx, nstm_idx, f_stm_idx, f_nstm_idx,
            ws_ft, ws_fft, ws_pidx, n_boards, nb_ft, nb_fft);
    }
    {   // sliced gather (128 B row requests)
        int groups = (n_boards + BPB - 1) / BPB;
        nnue_gather<<<groups * NSLICE, 1024, lds_bytes, stream>>>(
            (const uint2*)ws_pidx, (const char*)ws_ft, (const char*)ws_fft,
            ft_b, fft_b, out_w, ws_part, n_boards);
    }
    {   // reduce partials + sigmoid
        nnue_final<<<(n_boards + 255) / 256, 256, 0, stream>>>(ws_part, out_b, out, n_boards);
    }
}